// Round 1
// baseline (229.666 us; speedup 1.0000x reference)
//
#include <hip/hip_runtime.h>
#include <math.h>

#define B_SEQ 65536
#define T_SEQ 34
#define VOCAB 14
#define SEQS_PER_BLK 16
#define ACTIVE (SEQS_PER_BLK * T_SEQ)   // 544
#define BLK_THREADS 576                  // 9 waves; tid 544..575 idle after sync
#define NBLK (B_SEQ / SEQS_PER_BLK)      // 4096
#define NSTATE (T_SEQ * VOCAB)           // 476 distinct (t, token) states

__device__ __forceinline__ void layernorm6(const float* x, const float* g,
                                           const float* bt, float* o) {
    float mu = (x[0] + x[1] + x[2] + x[3] + x[4] + x[5]) * (1.0f / 6.0f);
    float var = 0.0f;
#pragma unroll
    for (int i = 0; i < 6; ++i) { float d = x[i] - mu; var += d * d; }
    var *= (1.0f / 6.0f);
    float rs = __builtin_amdgcn_rsqf(var + 1e-5f);
#pragma unroll
    for (int i = 0; i < 6; ++i) o[i] = (x[i] - mu) * rs * g[i] + bt[i];
}

__global__ __launch_bounds__(BLK_THREADS, 7) void fused_tf_kernel(
    const int* __restrict__ idx,
    const float* __restrict__ tok_emb,
    const float* __restrict__ pos_enc,
    const float* __restrict__ wq,
    const float* __restrict__ wk,
    const float* __restrict__ wv,
    const float* __restrict__ wo,
    const float* __restrict__ ln1_g, const float* __restrict__ ln1_b,
    const float* __restrict__ ln2_g, const float* __restrict__ ln2_b,
    const float* __restrict__ w1,   const float* __restrict__ b1,
    const float* __restrict__ w2,   const float* __restrict__ b2,
    const float* __restrict__ lnf_g, const float* __restrict__ lnf_b,
    const float* __restrict__ w_head,
    float* __restrict__ out)
{
    // kv table: [t][vocab][12] = k(h0:3,h1:3), v(h0:3,h1:3). stride 48 B (16-B
    // aligned, proven conflict-free). q table separate: pre-scaled by
    // 1/sqrt(3)*log2(e) so scores feed v_exp_f32 directly.
    __shared__ __align__(16) float kvtab[NSTATE * 12];   // 22.8 KB
    __shared__ float qtab[NSTATE * 6];                   // 11.4 KB
    __shared__ unsigned pk_lds[SEQS_PER_BLK * 5];        // nibble-packed tokens

    const int tid = threadIdx.x;

    // ---- build (t,tok) -> (k,v,q) tables: 476 distinct token states ----
    if (tid < NSTATE) {
        const int e = tid;
        const int t = e / VOCAB;
        const int v = e - t * VOCAB;
        float x[6];
#pragma unroll
        for (int i = 0; i < 3; ++i) x[i] = tok_emb[v * 3 + i];
#pragma unroll
        for (int i = 0; i < 3; ++i) x[3 + i] = pos_enc[t * 3 + i];
        float xl[6];
        layernorm6(x, ln1_g, ln1_b, xl);
        float* dst = &kvtab[e * 12];
        const float qs = 0.57735026918962576f * 1.4426950408889634f; // 1/sqrt(3)*log2e
#pragma unroll
        for (int j = 0; j < 6; ++j) {
            dst[j]     = xl[3] * wk[j] + xl[4] * wk[6 + j] + xl[5] * wk[12 + j];
            dst[6 + j] = xl[0] * wv[j] + xl[1] * wv[6 + j] + xl[2] * wv[12 + j];
            qtab[e * 6 + j] =
                (xl[3] * wq[j] + xl[4] * wq[6 + j] + xl[5] * wq[12 + j]) * qs;
        }
    }
    // ---- pack tokens: 4 bits each, 8 per word, 5 words per sequence ----
    if (tid < SEQS_PER_BLK * 5) {
        const int sq = tid / 5;
        const int w  = tid - sq * 5;
        const int* p = idx + (size_t)blockIdx.x * ACTIVE + sq * T_SEQ + w * 8;
        const int n = (w == 4) ? 2 : 8;   // word 4 holds tokens 32,33 only
        unsigned pk = 0;
        for (int j = 0; j < n; ++j) pk |= ((unsigned)p[j]) << (4 * j);
        pk_lds[tid] = pk;
    }
    __syncthreads();

    if (tid >= ACTIVE) return;   // no further barriers

    // lane map: 16 seqs x 4 consecutive t per wave; descending t so the
    // half-idle 9th wave gets the shortest loops.
    const int seq = tid & 15;
    const int t   = 33 - (tid >> 4);
    const int b   = blockIdx.x * SEQS_PER_BLK + seq;
    const int g   = b * T_SEQ + t;

    // whole token history in 5 registers -> every kv address in the loop is
    // register-computable; no per-iteration LDS dependency chain.
    const unsigned pk0 = pk_lds[seq * 5 + 0];
    const unsigned pk1 = pk_lds[seq * 5 + 1];
    const unsigned pk2 = pk_lds[seq * 5 + 2];
    const unsigned pk3 = pk_lds[seq * 5 + 3];
    const unsigned pk4 = pk_lds[seq * 5 + 4];

    // my token from the packed words (select tree, no LDS read)
    const unsigned selA = (t < 8)  ? pk0 : pk1;
    const unsigned selB = (t < 24) ? pk2 : pk3;
    unsigned sel = (t < 16) ? selA : selB;
    sel = (t < 32) ? sel : pk4;
    const int mytok = (int)((sel >> ((t & 7) * 4)) & 15u);

    // pre-scaled q from table
    const int e_my = t * VOCAB + mytok;
    float q[6];
    {
        const float2* qp = (const float2*)&qtab[e_my * 6];
        const float2 q01 = qp[0], q23 = qp[1], q45 = qp[2];
        q[0] = q01.x; q[1] = q01.y; q[2] = q23.x;
        q[3] = q23.y; q[4] = q45.x; q[5] = q45.y;
    }

    // ---- causal attention: 5 static groups of 8 unrolled slots.
    // group executes if any lane needs it (exec mask); per-lane tail handled
    // by the (s<=t) cndmask on p. scores bounded -> no max-subtract.
    float den0 = 0.0f, den1 = 0.0f;
    float a0 = 0.f, a1 = 0.f, a2 = 0.f, a3 = 0.f, a4 = 0.f, a5 = 0.f;
    const char* kb = (const char*)kvtab;

#define SLOT(s_, pw_, sh_) {                                                  \
    const int tk = (int)(((pw_) >> (sh_)) & 15u);                             \
    const char* ep = kb + tk * 48 + (s_) * 672;                               \
    const float4 ea = *(const float4*)(ep);        /* k0.xyz k1.x  */         \
    const float4 eb = *(const float4*)(ep + 16);   /* k1.yz v0.xy  */         \
    const float4 ec = *(const float4*)(ep + 32);   /* v0.z  v1.xyz */         \
    const float s0 = q[0] * ea.x + q[1] * ea.y + q[2] * ea.z;                 \
    const float s1 = q[3] * ea.w + q[4] * eb.x + q[5] * eb.y;                 \
    const float p0 = ((s_) <= t) ? __builtin_amdgcn_exp2f(s0) : 0.0f;         \
    const float p1 = ((s_) <= t) ? __builtin_amdgcn_exp2f(s1) : 0.0f;         \
    den0 += p0; den1 += p1;                                                   \
    a0 += p0 * eb.z; a1 += p0 * eb.w; a2 += p0 * ec.x;                        \
    a3 += p1 * ec.y; a4 += p1 * ec.z; a5 += p1 * ec.w; }

#define GROUP8(g_, pw_) if (t >= (g_) * 8) {                                  \
    SLOT((g_) * 8 + 0, pw_, 0)  SLOT((g_) * 8 + 1, pw_, 4)                    \
    SLOT((g_) * 8 + 2, pw_, 8)  SLOT((g_) * 8 + 3, pw_, 12)                   \
    SLOT((g_) * 8 + 4, pw_, 16) SLOT((g_) * 8 + 5, pw_, 20)                   \
    SLOT((g_) * 8 + 6, pw_, 24) SLOT((g_) * 8 + 7, pw_, 28) }

    GROUP8(0, pk0)
    GROUP8(1, pk1)
    GROUP8(2, pk2)
    GROUP8(3, pk3)
    if (t >= 32) { SLOT(32, pk4, 0) SLOT(33, pk4, 4) }

#undef GROUP8
#undef SLOT

    const float inv0 = __builtin_amdgcn_rcpf(den0);
    const float inv1 = __builtin_amdgcn_rcpf(den1);
    float ao[6];
    ao[0] = a0 * inv0; ao[1] = a1 * inv0; ao[2] = a2 * inv0;
    ao[3] = a3 * inv1; ao[4] = a4 * inv1; ao[5] = a5 * inv1;

    // ---- residual input x (needed only from here on; loads sink past loop) ----
    float x[6];
#pragma unroll
    for (int i = 0; i < 3; ++i) x[i] = tok_emb[mytok * 3 + i];
#pragma unroll
    for (int i = 0; i < 3; ++i) x[3 + i] = pos_enc[t * 3 + i];

    // ---- attn out proj + residual ----
    float x2[6];
#pragma unroll
    for (int j = 0; j < 6; ++j) {
        float s = x[j];
#pragma unroll
        for (int i = 0; i < 6; ++i) s += ao[i] * wo[i * 6 + j];
        x2[j] = s;
    }

    // ---- FFN ----
    float h[6];
    layernorm6(x2, ln2_g, ln2_b, h);
    float f[6];
#pragma unroll
    for (int j = 0; j < 6; ++j) {
        float s = b1[j];
#pragma unroll
        for (int i = 0; i < 6; ++i) s += h[i] * w1[i * 6 + j];
        f[j] = 0.5f * s * (1.0f + erff(s * 0.70710678118654752f));
    }
    float x3[6];
#pragma unroll
    for (int j = 0; j < 6; ++j) {
        float s = x2[j] + b2[j];
#pragma unroll
        for (int i = 0; i < 6; ++i) s += f[i] * w2[i * 6 + j];
        x3[j] = s;
    }

    // ---- final LN + head ----
    float xo[6];
    layernorm6(x3, lnf_g, lnf_b, xo);
    float o[14];
#pragma unroll
    for (int j = 0; j < 14; ++j) {
        float s = 0.0f;
#pragma unroll
        for (int i = 0; i < 6; ++i) s += xo[i] * w_head[i * 14 + j];
        o[j] = s;
    }

    // per-wave: 16 clusters of 4 rows x 56 B = 224 contiguous B each.
    float2* op = (float2*)(out + (size_t)g * 14);
#pragma unroll
    for (int j = 0; j < 7; ++j) op[j] = make_float2(o[2 * j], o[2 * j + 1]);
}

extern "C" void kernel_launch(void* const* d_in, const int* in_sizes, int n_in,
                              void* d_out, int out_size, void* d_ws, size_t ws_size,
                              hipStream_t stream) {
    const int*   idx     = (const int*)d_in[0];
    const float* tok_emb = (const float*)d_in[1];
    const float* pos_enc = (const float*)d_in[2];
    const float* wq      = (const float*)d_in[3];
    const float* wk      = (const float*)d_in[4];
    const float* wv      = (const float*)d_in[5];
    const float* wo      = (const float*)d_in[6];
    const float* ln1_g   = (const float*)d_in[7];
    const float* ln1_b   = (const float*)d_in[8];
    const float* ln2_g   = (const float*)d_in[9];
    const float* ln2_b   = (const float*)d_in[10];
    const float* w1      = (const float*)d_in[11];
    const float* b1      = (const float*)d_in[12];
    const float* w2      = (const float*)d_in[13];
    const float* b2      = (const float*)d_in[14];
    const float* lnf_g   = (const float*)d_in[15];
    const float* lnf_b   = (const float*)d_in[16];
    const float* w_head  = (const float*)d_in[17];
    float* out = (float*)d_out;

    hipLaunchKernelGGL(fused_tf_kernel, dim3(NBLK), dim3(BLK_THREADS), 0, stream,
                       idx, tok_emb, pos_enc, wq, wk, wv, wo,
                       ln1_g, ln1_b, ln2_g, ln2_b, w1, b1, w2, b2,
                       lnf_g, lnf_b, w_head, out);
}

// Round 2
// 217.583 us; speedup vs baseline: 1.0555x; 1.0555x over previous
//
#include <hip/hip_runtime.h>
#include <math.h>

typedef float v2f __attribute__((ext_vector_type(2)));

#define B_SEQ 65536
#define T_SEQ 34
#define VOCAB 14
#define SEQS_PER_BLK 16
#define ACTIVE (SEQS_PER_BLK * T_SEQ)   // 544
#define BLK_THREADS 576                  // 9 waves; tid 544..575 idle after sync
#define NBLK (B_SEQ / SEQS_PER_BLK)      // 4096
#define NSTATE (T_SEQ * VOCAB)           // 476 distinct (t, token) states

__device__ __forceinline__ void layernorm6(const float* x, const float* g,
                                           const float* bt, float* o) {
    float mu = (x[0] + x[1] + x[2] + x[3] + x[4] + x[5]) * (1.0f / 6.0f);
    float var = 0.0f;
#pragma unroll
    for (int i = 0; i < 6; ++i) { float d = x[i] - mu; var += d * d; }
    var *= (1.0f / 6.0f);
    float rs = __builtin_amdgcn_rsqf(var + 1e-5f);
#pragma unroll
    for (int i = 0; i < 6; ++i) o[i] = (x[i] - mu) * rs * g[i] + bt[i];
}

// packed layernorm over 3 feature pairs -> v_pk_* ops
__device__ __forceinline__ void ln6p(const v2f* x, const float* g,
                                     const float* bt, v2f* o) {
    v2f s2 = x[0] + x[1] + x[2];
    float mu = (s2.x + s2.y) * (1.0f / 6.0f);
    v2f d0 = x[0] - mu, d1 = x[1] - mu, d2 = x[2] - mu;
    v2f vv = d0 * d0 + d1 * d1 + d2 * d2;
    float var = (vv.x + vv.y) * (1.0f / 6.0f);
    float rs = __builtin_amdgcn_rsqf(var + 1e-5f);
    const v2f* g2 = (const v2f*)g;
    const v2f* b2 = (const v2f*)bt;
    o[0] = d0 * rs * g2[0] + b2[0];
    o[1] = d1 * rs * g2[1] + b2[1];
    o[2] = d2 * rs * g2[2] + b2[2];
}

// packed exact-ish gelu: erf via A&S 7.1.26 (|eps| <= 1.5e-7)
__device__ __forceinline__ v2f gelu2(v2f s) {
    const float pc = 0.3275911f;
    const float a1 = 0.254829592f, a2 = -0.284496736f, a3 = 1.421413741f,
                a4 = -1.453152027f, a5 = 1.061405429f;
    v2f ax; ax.x = fabsf(s.x); ax.y = fabsf(s.y);
    v2f xe = ax * 0.70710678118654752f;          // |s|/sqrt(2)
    v2f dn = xe * pc + 1.0f;
    v2f t;  t.x = __builtin_amdgcn_rcpf(dn.x); t.y = __builtin_amdgcn_rcpf(dn.y);
    v2f poly = ((((a5 * t + a4) * t + a3) * t + a2) * t + a1) * t;
    v2f ea = xe * xe * -1.4426950408889634f;     // -x^2 * log2(e)
    v2f ee; ee.x = __builtin_amdgcn_exp2f(ea.x); ee.y = __builtin_amdgcn_exp2f(ea.y);
    v2f er = 1.0f - poly * ee;                   // erf(|x|)
    v2f es; es.x = copysignf(er.x, s.x); es.y = copysignf(er.y, s.y);
    return 0.5f * s * (1.0f + es);
}

__global__ __launch_bounds__(BLK_THREADS, 7) void fused_tf_kernel(
    const int* __restrict__ idx,
    const float* __restrict__ tok_emb,
    const float* __restrict__ pos_enc,
    const float* __restrict__ wq,
    const float* __restrict__ wk,
    const float* __restrict__ wv,
    const float* __restrict__ wo,
    const float* __restrict__ ln1_g, const float* __restrict__ ln1_b,
    const float* __restrict__ ln2_g, const float* __restrict__ ln2_b,
    const float* __restrict__ w1,   const float* __restrict__ b1,
    const float* __restrict__ w2,   const float* __restrict__ b2,
    const float* __restrict__ lnf_g, const float* __restrict__ lnf_b,
    const float* __restrict__ w_head,
    float* __restrict__ out)
{
    // kv table interleaved by head: [t][vocab][ (k0x,k1x)(k0y,k1y)(k0z,k1z)
    // (v0x,v1x)(v0y,v1y)(v0z,v1z) ].  stride 48 B, 16-B aligned -> 3x
    // ds_read_b128 per slot, pairs feed v_pk_fma_f32 directly.
    __shared__ __align__(16) float kvtab[NSTATE * 12];   // 22.8 KB
    __shared__ unsigned pk_lds[SEQS_PER_BLK * 5];        // nibble-packed tokens

    const int tid = threadIdx.x;

    // ---- build (t,tok) -> (k,v) table: 476 distinct token states ----
    if (tid < NSTATE) {
        const int e = tid;
        const int tt = e / VOCAB;
        const int v = e - tt * VOCAB;
        float x0[6];
#pragma unroll
        for (int i = 0; i < 3; ++i) x0[i] = tok_emb[v * 3 + i];
#pragma unroll
        for (int i = 0; i < 3; ++i) x0[3 + i] = pos_enc[tt * 3 + i];
        float xl[6];
        layernorm6(x0, ln1_g, ln1_b, xl);
        float kc[6], vc[6];
#pragma unroll
        for (int j = 0; j < 6; ++j) {
            kc[j] = xl[3] * wk[j] + xl[4] * wk[6 + j] + xl[5] * wk[12 + j];
            vc[j] = xl[0] * wv[j] + xl[1] * wv[6 + j] + xl[2] * wv[12 + j];
        }
        float4* dst = (float4*)&kvtab[e * 12];
        dst[0] = make_float4(kc[0], kc[3], kc[1], kc[4]);
        dst[1] = make_float4(kc[2], kc[5], vc[0], vc[3]);
        dst[2] = make_float4(vc[1], vc[4], vc[2], vc[5]);
    }
    // ---- pack tokens: 4 bits each, 8 per word, 5 words per sequence ----
    if (tid < SEQS_PER_BLK * 5) {
        const int sq = tid / 5;
        const int w  = tid - sq * 5;
        const int* p = idx + (size_t)blockIdx.x * ACTIVE + sq * T_SEQ + w * 8;
        const int n = (w == 4) ? 2 : 8;
        unsigned pk = 0;
        for (int j = 0; j < n; ++j) pk |= ((unsigned)p[j]) << (4 * j);
        pk_lds[tid] = pk;
    }
    __syncthreads();

    if (tid >= ACTIVE) return;   // no further barriers

    // lane map: 16 seqs x 4 consecutive t per wave, descending t.
    const int seq = tid & 15;
    const int t   = 33 - (tid >> 4);
    const int b   = blockIdx.x * SEQS_PER_BLK + seq;
    const int g   = b * T_SEQ + t;

    // wave-uniform t range -> uniform full/masked branch selection
    const int wv_id = tid >> 6;           // 0..8
    const int tmaxw = 33 - 4 * wv_id;
    const int tminw = tmaxw - 3;

    // whole token history in 5 registers
    const unsigned pk0 = pk_lds[seq * 5 + 0];
    const unsigned pk1 = pk_lds[seq * 5 + 1];
    const unsigned pk2 = pk_lds[seq * 5 + 2];
    const unsigned pk3 = pk_lds[seq * 5 + 3];
    const unsigned pk4 = pk_lds[seq * 5 + 4];

    // my token (select tree, no LDS read)
    const unsigned selA = (t < 8)  ? pk0 : pk1;
    const unsigned selB = (t < 24) ? pk2 : pk3;
    unsigned sel = (t < 16) ? selA : selB;
    sel = (t < 32) ? sel : pk4;
    const int mytok = (int)((sel >> ((t & 7) * 4)) & 15u);

    // own x, LN1, q (pre-scaled into log2 domain)
    float x[6];
#pragma unroll
    for (int i = 0; i < 3; ++i) x[i] = tok_emb[mytok * 3 + i];
#pragma unroll
    for (int i = 0; i < 3; ++i) x[3 + i] = pos_enc[t * 3 + i];
    float xl[6];
    layernorm6(x, ln1_g, ln1_b, xl);
    const float qs = 0.57735026918962576f * 1.4426950408889634f; // 1/sqrt(3)*log2e
    float qc[6];
#pragma unroll
    for (int j = 0; j < 6; ++j)
        qc[j] = (xl[3] * wq[j] + xl[4] * wq[6 + j] + xl[5] * wq[12 + j]) * qs;
    v2f qx = {qc[0], qc[3]}, qy = {qc[1], qc[4]}, qz = {qc[2], qc[5]};

    // ---- causal attention: packed over heads, depth-2 load pipeline ----
    v2f den = {0.0f, 0.0f};
    v2f A0 = {0.0f, 0.0f}, A1 = {0.0f, 0.0f}, A2 = {0.0f, 0.0f};
    const char* kb = (const char*)kvtab;

#define KV_LOAD(s_, pw_, sh_, EA, EB, EC) {                                   \
    const int tk_ = (int)(((pw_) >> (sh_)) & 15u);                            \
    const float4* ep_ = (const float4*)(kb + tk_ * 48 + (s_) * 672);          \
    EA = ep_[0]; EB = ep_[1]; EC = ep_[2]; }

#define KV_MATH(s_, EA, EB, EC, MASKED) {                                     \
    v2f kx_ = {EA.x, EA.y}, ky_ = {EA.z, EA.w}, kz_ = {EB.x, EB.y};           \
    v2f vx_ = {EB.z, EB.w}, vy_ = {EC.x, EC.y}, vz_ = {EC.z, EC.w};           \
    v2f sc_ = qx * kx_ + qy * ky_ + qz * kz_;                                 \
    v2f p_;                                                                   \
    p_.x = __builtin_amdgcn_exp2f(sc_.x);                                     \
    p_.y = __builtin_amdgcn_exp2f(sc_.y);                                     \
    if (MASKED) {                                                             \
        const bool ok_ = ((s_) <= t);                                         \
        p_.x = ok_ ? p_.x : 0.0f; p_.y = ok_ ? p_.y : 0.0f;                   \
    }                                                                         \
    den += p_; A0 += p_ * vx_; A1 += p_ * vy_; A2 += p_ * vz_; }

#define SLOT2(sA, shA, sB, shB, pw_, MASKED) {                                \
    float4 eaA, ebA, ecA, eaB, ebB, ecB;                                      \
    KV_LOAD(sA, pw_, shA, eaA, ebA, ecA)                                      \
    KV_LOAD(sB, pw_, shB, eaB, ebB, ecB)                                      \
    KV_MATH(sA, eaA, ebA, ecA, MASKED)                                        \
    KV_MATH(sB, eaB, ebB, ecB, MASKED) }

#define GROUP8(g_, pw_)                                                       \
    if (tminw >= (g_) * 8 + 7) {        /* all lanes cover whole group */     \
        SLOT2((g_)*8+0, 0,  (g_)*8+1, 4,  pw_, 0)                             \
        SLOT2((g_)*8+2, 8,  (g_)*8+3, 12, pw_, 0)                             \
        SLOT2((g_)*8+4, 16, (g_)*8+5, 20, pw_, 0)                             \
        SLOT2((g_)*8+6, 24, (g_)*8+7, 28, pw_, 0)                             \
    } else if (tmaxw >= (g_) * 8) {     /* boundary group: 2-slot gating */   \
        SLOT2((g_)*8+0, 0,  (g_)*8+1, 4,  pw_, 1)                             \
        if (tmaxw >= (g_)*8+2) { SLOT2((g_)*8+2, 8,  (g_)*8+3, 12, pw_, 1) }  \
        if (tmaxw >= (g_)*8+4) { SLOT2((g_)*8+4, 16, (g_)*8+5, 20, pw_, 1) }  \
        if (tmaxw >= (g_)*8+6) { SLOT2((g_)*8+6, 24, (g_)*8+7, 28, pw_, 1) }  \
    }

    GROUP8(0, pk0)
    GROUP8(1, pk1)
    GROUP8(2, pk2)
    GROUP8(3, pk3)
    if (tmaxw >= 32) { SLOT2(32, 0, 33, 4, pk4, 1) }

#undef GROUP8
#undef SLOT2
#undef KV_MATH
#undef KV_LOAD

    v2f inv;
    inv.x = __builtin_amdgcn_rcpf(den.x);
    inv.y = __builtin_amdgcn_rcpf(den.y);
    v2f aox = A0 * inv, aoy = A1 * inv, aoz = A2 * inv;  // (ao0,ao3)(ao1,ao4)(ao2,ao5)
    float ao[6] = {aox.x, aoy.x, aoz.x, aox.y, aoy.y, aoz.y};

    // ---- attn out proj + residual (packed over output pairs) ----
    const v2f* wo2 = (const v2f*)wo;         // row i -> wo2[i*3 + k]
    v2f X2[3] = { {x[0], x[1]}, {x[2], x[3]}, {x[4], x[5]} };
#pragma unroll
    for (int i = 0; i < 6; ++i) {
        X2[0] += ao[i] * wo2[i * 3 + 0];
        X2[1] += ao[i] * wo2[i * 3 + 1];
        X2[2] += ao[i] * wo2[i * 3 + 2];
    }

    // ---- FFN (packed) ----
    v2f H[3];
    ln6p(X2, ln2_g, ln2_b, H);
    float h[6] = {H[0].x, H[0].y, H[1].x, H[1].y, H[2].x, H[2].y};
    const v2f* w1v = (const v2f*)w1;
    const v2f* b1v = (const v2f*)b1;
    v2f F[3] = { b1v[0], b1v[1], b1v[2] };
#pragma unroll
    for (int i = 0; i < 6; ++i) {
        F[0] += h[i] * w1v[i * 3 + 0];
        F[1] += h[i] * w1v[i * 3 + 1];
        F[2] += h[i] * w1v[i * 3 + 2];
    }
    F[0] = gelu2(F[0]); F[1] = gelu2(F[1]); F[2] = gelu2(F[2]);
    float f[6] = {F[0].x, F[0].y, F[1].x, F[1].y, F[2].x, F[2].y};
    const v2f* w2v = (const v2f*)w2;
    const v2f* b2v = (const v2f*)b2;
    v2f X3[3] = { X2[0] + b2v[0], X2[1] + b2v[1], X2[2] + b2v[2] };
#pragma unroll
    for (int i = 0; i < 6; ++i) {
        X3[0] += f[i] * w2v[i * 3 + 0];
        X3[1] += f[i] * w2v[i * 3 + 1];
        X3[2] += f[i] * w2v[i * 3 + 2];
    }

    // ---- final LN + head (packed over 7 output pairs) ----
    v2f XO[3];
    ln6p(X3, lnf_g, lnf_b, XO);
    float xo[6] = {XO[0].x, XO[0].y, XO[1].x, XO[1].y, XO[2].x, XO[2].y};
    const v2f* whv = (const v2f*)w_head;     // row i -> whv[i*7 + j]
    v2f O[7] = {{0,0},{0,0},{0,0},{0,0},{0,0},{0,0},{0,0}};
#pragma unroll
    for (int i = 0; i < 6; ++i) {
#pragma unroll
        for (int j = 0; j < 7; ++j) O[j] += xo[i] * whv[i * 7 + j];
    }

    // per-wave: 16 clusters of 4 rows x 56 B contiguous each.
    v2f* op = (v2f*)(out + (size_t)g * 14);
#pragma unroll
    for (int j = 0; j < 7; ++j) op[j] = O[j];
}

extern "C" void kernel_launch(void* const* d_in, const int* in_sizes, int n_in,
                              void* d_out, int out_size, void* d_ws, size_t ws_size,
                              hipStream_t stream) {
    const int*   idx     = (const int*)d_in[0];
    const float* tok_emb = (const float*)d_in[1];
    const float* pos_enc = (const float*)d_in[2];
    const float* wq      = (const float*)d_in[3];
    const float* wk      = (const float*)d_in[4];
    const float* wv      = (const float*)d_in[5];
    const float* wo      = (const float*)d_in[6];
    const float* ln1_g   = (const float*)d_in[7];
    const float* ln1_b   = (const float*)d_in[8];
    const float* ln2_g   = (const float*)d_in[9];
    const float* ln2_b   = (const float*)d_in[10];
    const float* w1      = (const float*)d_in[11];
    const float* b1      = (const float*)d_in[12];
    const float* w2      = (const float*)d_in[13];
    const float* b2      = (const float*)d_in[14];
    const float* lnf_g   = (const float*)d_in[15];
    const float* lnf_b   = (const float*)d_in[16];
    const float* w_head  = (const float*)d_in[17];
    float* out = (float*)d_out;

    hipLaunchKernelGGL(fused_tf_kernel, dim3(NBLK), dim3(BLK_THREADS), 0, stream,
                       idx, tok_emb, pos_enc, wq, wk, wv, wo,
                       ln1_g, ln1_b, ln2_g, ln2_b, w1, b1, w2, b2,
                       lnf_g, lnf_b, w_head, out);
}